// Round 2
// baseline (308.379 us; speedup 1.0000x reference)
//
#include <hip/hip_runtime.h>
#include <hip/hip_bf16.h>

#define BB 2
#define NN 384
#define TFD 22
#define POSD 32
#define TPROJ 33
#define CS 256
#define CZ 128
#define PI_F 3.14159265358979323846f

typedef __hip_bfloat16 bf16;
typedef __attribute__((ext_vector_type(8))) short short8;
typedef __attribute__((ext_vector_type(4))) float floatx4;

__device__ __forceinline__ float bfbits2f(unsigned short u) {
  unsigned v = ((unsigned)u) << 16;
  float f;
  __builtin_memcpy(&f, &v, 4);
  return f;
}
__device__ __forceinline__ unsigned short f2bf(float x) {
  bf16 h = __float2bfloat16(x);
  unsigned short u;
  __builtin_memcpy(&u, &h, 2);
  return u;
}
__device__ __forceinline__ bool probe_f32(const void* fm) {
  return *(const unsigned*)fm == 0x3F800000u;
}

// ---- ws layout (float units) ----
#define TAB_OFF 0            // 2048*128 = 262144 (tab incl. all three edge biases)
#define SEQ0_OFF 262144      // 768*256
#define EL_OFF 458752        // 768*128
#define ER_OFF 557056        // 768*128
#define P_OFF 655360         // fp32 params, 60802
#define WB_OFF 716288        // bf16 (ushort) weight region: 163840 ushorts
// param-relative offsets
#define pSEQF 0
#define pTS 16896
#define pFM 16898
#define pWNPOS 17666
#define pBNPOS 25858
#define pWNTF 26114
#define pBNTF 31746
#define pWNTIME 32002
#define pBNTIME 40450
#define pBN1 40706
#define pBN2 40962
#define pGN 41218
#define pBEN 41474
#define pWEPOS 41730
#define pBEPOS 45826
#define pWETF 45954
#define pBETF 51586
#define pWETIME 51714
#define pBETIME 60162
#define pBE1 60290
#define pBE2 60418
#define pGE 60546
#define pBEE 60674
// ushort-relative offsets in WB region
#define UB_WE1 0
#define UB_WE2 16384
#define UB_WN1 32768
#define UB_WN2 98304

struct InPtrs { const void* p[28]; };

// Convert all float params to fp32 (region P) and the 4 MLP weights to bf16 (region WB),
// interpreting inputs as fp32 or bf16 per the frame_mask probe.
__global__ void cvt_all(InPtrs ip, float* __restrict__ ws) {
  const int idx = blockIdx.x * 256 + threadIdx.x;
  if (idx >= 224642) return;
  const int srci[27] = {1,2,3,4,5,6,7,8,9,11,13,14,15,16,17,18,19,20,21,23,25,26,27,22,24,10,12};
  const int pre[28] = {0,16896,16898,17666,25858,26114,31746,32002,40450,40706,40962,41218,41474,
                       41730,45826,45954,51586,51714,60162,60290,60418,60546,60674,60802,
                       77186,93570,159106,224642};
  const bool f32 = probe_f32(ip.p[3]);
  int e = 0;
  while (idx >= pre[e + 1]) ++e;
  const int j = idx - pre[e];
  const void* sp = ip.p[srci[e]];
  if (e < 23) {
    float v = f32 ? ((const float*)sp)[j] : bfbits2f(((const unsigned short*)sp)[j]);
    ws[P_OFF + pre[e] + j] = v;
  } else {
    const int ub[4] = {UB_WE1, UB_WE2, UB_WN1, UB_WN2};
    unsigned short* wb = (unsigned short*)(ws + WB_OFF);
    wb[ub[e - 23] + j] = f32 ? f2bf(((const float*)sp)[j]) : ((const unsigned short*)sp)[j];
  }
}

// tab[rel+1024][c] = index_emb(rel) @ W_epos[c]^T + b_epos[c] + b_etf[c] + b_etime[c]
__global__ void tab_kernel(float* __restrict__ ws) {
  const float* P = ws + P_OFF;
  __shared__ float pe[POSD];
  int r = blockIdx.x, t = threadIdx.x;  // 128 threads
  if (t < 16) {
    float ang = (float)(r - 1024) * PI_F * powf(2056.0f, -(float)t * (1.0f / 16.0f));
    pe[t] = sinf(ang);
    pe[t + 16] = cosf(ang);
  }
  __syncthreads();
  float acc = P[pBEPOS + t] + P[pBETF + t] + P[pBETIME + t];
  const float* w = P + pWEPOS + t * POSD;
#pragma unroll
  for (int k = 0; k < POSD; ++k) acc += pe[k] * w[k];
  ws[TAB_OFF + r * CZ + t] = acc;
}

// Per-node: seq0[bn][256] (node pre-MLP sum incl. biases), eL[bn][128], eR[bn][128].
__global__ void nodeprep(const int* __restrict__ seq_idx, float* __restrict__ ws) {
  const float* P = ws + P_OFF;
  __shared__ float pe[POSD];
  __shared__ float temb[TPROJ];
  __shared__ float sf[TFD];
  int bn = blockIdx.x, t = threadIdx.x;  // 256 threads
  int b = bn / NN;
  float fm = P[pFM + bn];
  if (t < 16) {
    float idxv = (float)seq_idx[bn];
    float ang = idxv * PI_F * powf(2056.0f, -(float)t * (1.0f / 16.0f));
    pe[t] = sinf(ang);
    pe[t + 16] = cosf(ang);
    float tres = P[pTS + b] * fm;
    float freq = expf(-(logf(10000.0f) * (1.0f / 15.0f)) * (float)t);
    temb[t] = sinf(tres * freq);
    temb[t + 16] = cosf(tres * freq);
  }
  if (t == 16) temb[32] = fm;
  if (t < TFD) sf[t] = P[pSEQF + bn * TFD + t];
  __syncthreads();
  {
    int c = t;  // 0..255
    float acc = P[pBNPOS + c] + P[pBNTF + c] + P[pBNTIME + c];
    const float* w = P + pWNPOS + c * POSD;
#pragma unroll
    for (int k = 0; k < POSD; ++k) acc += pe[k] * w[k];
    const float* w2 = P + pWNTF + c * TFD;
#pragma unroll
    for (int k = 0; k < TFD; ++k) acc += sf[k] * w2[k];
    const float* w3 = P + pWNTIME + c * TPROJ;
#pragma unroll
    for (int k = 0; k < TPROJ; ++k) acc += temb[k] * w3[k];
    ws[SEQ0_OFF + bn * CS + c] = acc;
  }
  if (t < CZ) {
    int c = t;
    float acc = 0.0f;
    const float* w = P + pWETF + c * (2 * TFD);
#pragma unroll
    for (int k = 0; k < TFD; ++k) acc += sf[k] * w[k];
    const float* w2 = P + pWETIME + c * (2 * TPROJ);
#pragma unroll
    for (int k = 0; k < TPROJ; ++k) acc += temb[k] * w2[k];
    ws[EL_OFF + bn * CZ + c] = acc;
  } else {
    int c = t - CZ;
    float acc = 0.0f;
    const float* w = P + pWETF + c * (2 * TFD) + TFD;
#pragma unroll
    for (int k = 0; k < TFD; ++k) acc += sf[k] * w[k];
    const float* w2 = P + pWETIME + c * (2 * TPROJ) + TPROJ;
#pragma unroll
    for (int k = 0; k < TPROJ; ++k) acc += temb[k] * w2[k];
    ws[ER_OFF + bn * CZ + c] = acc;
  }
}

// ---- Node MLP via MFMA: 32 rows/block, C=256, 2 layers + LN. 24 blocks x 256 thr. ----
__global__ __launch_bounds__(256) void node_mfma(const float* __restrict__ ws,
                                                 const void* __restrict__ fmraw,
                                                 void* __restrict__ outv) {
  __shared__ __align__(16) unsigned short sA0[32][CS + 8];
  __shared__ __align__(16) unsigned short sA1[32][CS + 8];
  __shared__ float sO[32][CS + 4];
  __shared__ float sRed[32][8], sRedQ[32][8], sMu[32], sRs[32];
  const float* P = ws + P_OFF;
  const unsigned short* WB = (const unsigned short*)(ws + WB_OFF);
  const unsigned short* W1 = WB + UB_WN1;
  const unsigned short* W2 = WB + UB_WN2;
  const int row0 = blockIdx.x * 32;
  const int t = threadIdx.x;
  const int wave = t >> 6, lane = t & 63, quad = lane >> 4, l16 = lane & 15;
  // input: relu(seq0)
  {
    const float* seq0 = ws + SEQ0_OFF;
#pragma unroll
    for (int r = 0; r < 32; ++r) sA0[r][t] = f2bf(fmaxf(seq0[(row0 + r) * CS + t], 0.0f));
  }
  __syncthreads();
  short8 af[2][8];
  floatx4 acc[2][4];
  // ---- layer 1 ----
#pragma unroll
  for (int mt = 0; mt < 2; ++mt)
#pragma unroll
    for (int ks = 0; ks < 8; ++ks)
      af[mt][ks] = *(const short8*)&sA0[mt * 16 + l16][ks * 32 + quad * 8];
#pragma unroll
  for (int mt = 0; mt < 2; ++mt)
#pragma unroll
    for (int n = 0; n < 4; ++n) acc[mt][n] = (floatx4){0.f, 0.f, 0.f, 0.f};
#pragma unroll
  for (int ntl = 0; ntl < 4; ++ntl) {
    int n0 = (wave * 4 + ntl) * 16;
#pragma unroll
    for (int ks = 0; ks < 8; ++ks) {
      short8 bfr = *(const short8*)&W1[(n0 + l16) * CS + ks * 32 + quad * 8];
      acc[0][ntl] = __builtin_amdgcn_mfma_f32_16x16x32_bf16(af[0][ks], bfr, acc[0][ntl], 0, 0, 0);
      acc[1][ntl] = __builtin_amdgcn_mfma_f32_16x16x32_bf16(af[1][ks], bfr, acc[1][ntl], 0, 0, 0);
    }
  }
#pragma unroll
  for (int ntl = 0; ntl < 4; ++ntl) {
    int n0 = (wave * 4 + ntl) * 16;
    float b1v = P[pBN1 + n0 + l16];
#pragma unroll
    for (int mt = 0; mt < 2; ++mt)
#pragma unroll
      for (int i = 0; i < 4; ++i)
        sA1[mt * 16 + quad * 4 + i][n0 + l16] = f2bf(fmaxf(acc[mt][ntl][i] + b1v, 0.0f));
  }
  __syncthreads();
  // ---- layer 2 ----
#pragma unroll
  for (int mt = 0; mt < 2; ++mt)
#pragma unroll
    for (int ks = 0; ks < 8; ++ks)
      af[mt][ks] = *(const short8*)&sA1[mt * 16 + l16][ks * 32 + quad * 8];
#pragma unroll
  for (int mt = 0; mt < 2; ++mt)
#pragma unroll
    for (int n = 0; n < 4; ++n) acc[mt][n] = (floatx4){0.f, 0.f, 0.f, 0.f};
#pragma unroll
  for (int ntl = 0; ntl < 4; ++ntl) {
    int n0 = (wave * 4 + ntl) * 16;
#pragma unroll
    for (int ks = 0; ks < 8; ++ks) {
      short8 bfr = *(const short8*)&W2[(n0 + l16) * CS + ks * 32 + quad * 8];
      acc[0][ntl] = __builtin_amdgcn_mfma_f32_16x16x32_bf16(af[0][ks], bfr, acc[0][ntl], 0, 0, 0);
      acc[1][ntl] = __builtin_amdgcn_mfma_f32_16x16x32_bf16(af[1][ks], bfr, acc[1][ntl], 0, 0, 0);
    }
  }
#pragma unroll
  for (int ntl = 0; ntl < 4; ++ntl) {
    int n0 = (wave * 4 + ntl) * 16;
    float b2v = P[pBN2 + n0 + l16];
#pragma unroll
    for (int mt = 0; mt < 2; ++mt)
#pragma unroll
      for (int i = 0; i < 4; ++i)
        sO[mt * 16 + quad * 4 + i][n0 + l16] = acc[mt][ntl][i] + b2v;
  }
  __syncthreads();
  // ---- LayerNorm ----
  {
    int r = t >> 3, seg = t & 7;
    float s = 0.f, q = 0.f;
#pragma unroll
    for (int k = 0; k < 32; ++k) { float v = sO[r][seg * 32 + k]; s += v; q += v * v; }
    sRed[r][seg] = s; sRedQ[r][seg] = q;
  }
  __syncthreads();
  if (t < 32) {
    float s = 0.f, q = 0.f;
#pragma unroll
    for (int k = 0; k < 8; ++k) { s += sRed[t][k]; q += sRedQ[t][k]; }
    float mu = s * (1.0f / CS);
    float var = q * (1.0f / CS) - mu * mu;
    sMu[t] = mu; sRs[t] = rsqrtf(var + 1e-5f);
  }
  __syncthreads();
  {
    float g = P[pGN + t], be = P[pBEN + t];
    if (probe_f32(fmraw)) {
      float* o = (float*)outv;
#pragma unroll
      for (int r = 0; r < 32; ++r)
        o[(size_t)(row0 + r) * CS + t] = (sO[r][t] - sMu[r]) * sRs[r] * g + be;
    } else {
      bf16* o = (bf16*)outv;
#pragma unroll
      for (int r = 0; r < 32; ++r)
        o[(size_t)(row0 + r) * CS + t] = __float2bfloat16((sO[r][t] - sMu[r]) * sRs[r] * g + be);
    }
  }
}

// ---- Edge MLP via MFMA: block = (b, i, 32 j's), C=128, 2 layers + LN. 9216 blocks. ----
__global__ __launch_bounds__(256) void edge_mfma(const int* __restrict__ seq_idx,
                                                 const float* __restrict__ ws,
                                                 const void* __restrict__ fmraw,
                                                 void* __restrict__ outv) {
  __shared__ __align__(16) unsigned short sA0[32][CZ + 8];
  __shared__ __align__(16) unsigned short sA1[32][CZ + 8];
  __shared__ float sO[32][CZ + 4];
  __shared__ int sRel[32];
  __shared__ float sRed[32][8], sRedQ[32][8], sMu[32], sRs[32];
  const float* tab = ws + TAB_OFF;
  const float* eL = ws + EL_OFF;
  const float* eR = ws + ER_OFF;
  const float* P = ws + P_OFF;
  const unsigned short* WB = (const unsigned short*)(ws + WB_OFF);
  const unsigned short* W1 = WB + UB_WE1;
  const unsigned short* W2 = WB + UB_WE2;
  const int bid = blockIdx.x;
  const int jt = bid % (NN / 32);
  const int rem = bid / (NN / 32);
  const int irow = rem % NN;
  const int b = rem / NN;
  const int j0 = jt * 32;
  const int t = threadIdx.x;
  const int wave = t >> 6, lane = t & 63, quad = lane >> 4, l16 = lane & 15;
  if (t < 32) {
    int rel = seq_idx[b * NN + irow] - seq_idx[b * NN + j0 + t] + 1024;
    sRel[t] = min(max(rel, 0), 2047);
  }
  __syncthreads();
  {
    int c = t & 127, rh = (t >> 7) * 16;
    float eLi = eL[(b * NN + irow) * CZ + c];
#pragma unroll
    for (int rr = 0; rr < 16; ++rr) {
      int r = rh + rr;
      float v = tab[sRel[r] * CZ + c] + eLi + eR[(b * NN + j0 + r) * CZ + c];
      sA0[r][c] = f2bf(fmaxf(v, 0.0f));
    }
  }
  __syncthreads();
  short8 af[2][4];
  floatx4 acc[2][2];
  // ---- layer 1 ----
#pragma unroll
  for (int mt = 0; mt < 2; ++mt)
#pragma unroll
    for (int ks = 0; ks < 4; ++ks)
      af[mt][ks] = *(const short8*)&sA0[mt * 16 + l16][ks * 32 + quad * 8];
#pragma unroll
  for (int mt = 0; mt < 2; ++mt)
#pragma unroll
    for (int n = 0; n < 2; ++n) acc[mt][n] = (floatx4){0.f, 0.f, 0.f, 0.f};
#pragma unroll
  for (int ntl = 0; ntl < 2; ++ntl) {
    int n0 = (wave * 2 + ntl) * 16;
#pragma unroll
    for (int ks = 0; ks < 4; ++ks) {
      short8 bfr = *(const short8*)&W1[(n0 + l16) * CZ + ks * 32 + quad * 8];
      acc[0][ntl] = __builtin_amdgcn_mfma_f32_16x16x32_bf16(af[0][ks], bfr, acc[0][ntl], 0, 0, 0);
      acc[1][ntl] = __builtin_amdgcn_mfma_f32_16x16x32_bf16(af[1][ks], bfr, acc[1][ntl], 0, 0, 0);
    }
  }
#pragma unroll
  for (int ntl = 0; ntl < 2; ++ntl) {
    int n0 = (wave * 2 + ntl) * 16;
    float b1v = P[pBE1 + n0 + l16];
#pragma unroll
    for (int mt = 0; mt < 2; ++mt)
#pragma unroll
      for (int i = 0; i < 4; ++i)
        sA1[mt * 16 + quad * 4 + i][n0 + l16] = f2bf(fmaxf(acc[mt][ntl][i] + b1v, 0.0f));
  }
  __syncthreads();
  // ---- layer 2 ----
#pragma unroll
  for (int mt = 0; mt < 2; ++mt)
#pragma unroll
    for (int ks = 0; ks < 4; ++ks)
      af[mt][ks] = *(const short8*)&sA1[mt * 16 + l16][ks * 32 + quad * 8];
#pragma unroll
  for (int mt = 0; mt < 2; ++mt)
#pragma unroll
    for (int n = 0; n < 2; ++n) acc[mt][n] = (floatx4){0.f, 0.f, 0.f, 0.f};
#pragma unroll
  for (int ntl = 0; ntl < 2; ++ntl) {
    int n0 = (wave * 2 + ntl) * 16;
#pragma unroll
    for (int ks = 0; ks < 4; ++ks) {
      short8 bfr = *(const short8*)&W2[(n0 + l16) * CZ + ks * 32 + quad * 8];
      acc[0][ntl] = __builtin_amdgcn_mfma_f32_16x16x32_bf16(af[0][ks], bfr, acc[0][ntl], 0, 0, 0);
      acc[1][ntl] = __builtin_amdgcn_mfma_f32_16x16x32_bf16(af[1][ks], bfr, acc[1][ntl], 0, 0, 0);
    }
  }
#pragma unroll
  for (int ntl = 0; ntl < 2; ++ntl) {
    int n0 = (wave * 2 + ntl) * 16;
    float b2v = P[pBE2 + n0 + l16];
#pragma unroll
    for (int mt = 0; mt < 2; ++mt)
#pragma unroll
      for (int i = 0; i < 4; ++i)
        sO[mt * 16 + quad * 4 + i][n0 + l16] = acc[mt][ntl][i] + b2v;
  }
  __syncthreads();
  // ---- LayerNorm ----
  {
    int r = t >> 3, seg = t & 7;
    float s = 0.f, q = 0.f;
#pragma unroll
    for (int k = 0; k < 16; ++k) { float v = sO[r][seg * 16 + k]; s += v; q += v * v; }
    sRed[r][seg] = s; sRedQ[r][seg] = q;
  }
  __syncthreads();
  if (t < 32) {
    float s = 0.f, q = 0.f;
#pragma unroll
    for (int k = 0; k < 8; ++k) { s += sRed[t][k]; q += sRedQ[t][k]; }
    float mu = s * (1.0f / CZ);
    float var = q * (1.0f / CZ) - mu * mu;
    sMu[t] = mu; sRs[t] = rsqrtf(var + 1e-5f);
  }
  __syncthreads();
  {
    int c = t & 127, rh = (t >> 7) * 16;
    float g = P[pGE + c], be = P[pBEE + c];
    size_t base = ((size_t)(b * NN + irow) * NN + j0) * CZ + c;
    if (probe_f32(fmraw)) {
      float* o = (float*)outv + (size_t)BB * NN * CS;
#pragma unroll
      for (int rr = 0; rr < 16; ++rr) {
        int r = rh + rr;
        o[base + (size_t)r * CZ] = (sO[r][c] - sMu[r]) * sRs[r] * g + be;
      }
    } else {
      bf16* o = (bf16*)outv + (size_t)BB * NN * CS;
#pragma unroll
      for (int rr = 0; rr < 16; ++rr) {
        int r = rh + rr;
        o[base + (size_t)r * CZ] = __float2bfloat16((sO[r][c] - sMu[r]) * sRs[r] * g + be);
      }
    }
  }
}

extern "C" void kernel_launch(void* const* d_in, const int* in_sizes, int n_in,
                              void* d_out, int out_size, void* d_ws, size_t ws_size,
                              hipStream_t stream) {
  (void)in_sizes; (void)n_in; (void)out_size; (void)ws_size;
  const int* seq_idx = (const int*)d_in[0];
  float* ws = (float*)d_ws;
  InPtrs ip;
  for (int i = 0; i < 28; ++i) ip.p[i] = d_in[i];
  hipLaunchKernelGGL(cvt_all, dim3(878), dim3(256), 0, stream, ip, ws);
  hipLaunchKernelGGL(tab_kernel, dim3(2048), dim3(CZ), 0, stream, ws);
  hipLaunchKernelGGL(nodeprep, dim3(BB * NN), dim3(CS), 0, stream, seq_idx, ws);
  hipLaunchKernelGGL(node_mfma, dim3(BB * NN / 32), dim3(256), 0, stream, ws, d_in[3], d_out);
  hipLaunchKernelGGL(edge_mfma, dim3(BB * NN * (NN / 32)), dim3(256), 0, stream,
                     seq_idx, ws, d_in[3], d_out);
}